// Round 3
// baseline (114.879 us; speedup 1.0000x reference)
//
#include <hip/hip_runtime.h>

// SIM hard search: per-column stream compaction of first K topic-matching
// values. L=2048, B=4096, K=256 nominal; derived at launch from sizes.
//
// Round 3: full occupancy + deep MLP.
//   Block = 1024 threads = 8 columns (fast dim) x 128 row-chunks of 16 rows.
//   Grid  = B/8 = 512 blocks -> 2 blocks/CU -> 32 waves/CU (100% occupancy).
//   CHUNK=16 is a template param so the 16 strided topic loads fully unroll
//   into one in-flight batch. Rank scan: 3-step stride-8 shuffle scan within
//   each wave (chunks 8w..8w+7 live in one wave, column = lane&7), one
//   barrier, then a serial sum of the <=15 preceding wave totals from LDS.

#define NCH 128   // row-chunks per column (all within one block)
#define CPB 8     // columns per block
#define BLOCK (NCH * CPB)   // 1024

template <int CHUNK>
__global__ __launch_bounds__(BLOCK) void simhs_kernel(
    const float* __restrict__ user_seq,
    const int*   __restrict__ topics,
    const int*   __restrict__ tgt_topic,
    float*       __restrict__ out,
    int L, int B, int K)
{
    __shared__ int s_tot[BLOCK / 64][CPB];   // per-wave, per-column totals

    const int t    = threadIdx.x;
    const int ci   = t & (CPB - 1);   // column within block (fast -> coalesced)
    const int ch   = t >> 3;          // chunk index 0..127 (global in block)
    const int w    = t >> 6;          // wave index 0..15
    const int lane = t & 63;
    const int col  = blockIdx.x * CPB + ci;
    const bool colOK = (col < B);

    // ---- Phase 0: zero-init this block's output columns ----
    if (colOK) {
        for (int k = ch; k < K; k += NCH)
            out[(size_t)k * B + col] = 0.0f;
    }

    const int tt = colOK ? tgt_topic[col] : -1;
    const int r0 = ch * CHUNK;

    // ---- Phase 1: scan CHUNK rows, build match mask (CHUNK <= 32) ----
    unsigned int m = 0u;
    if (colOK) {
        const int* tp = topics + (size_t)r0 * B + col;
        #pragma unroll
        for (int i = 0; i < CHUNK; ++i) {
            if (r0 + i < L) {
                int v = tp[(size_t)i * B];
                m |= (v == tt ? 1u : 0u) << i;
            }
        }
    }
    const int cnt = __popc(m);

    // ---- Phase 2a: wave-level inclusive scan over this wave's 8 chunks.
    // Lanes are [localch(3b) | ci(3b)]; stride-8 shuffles stay in-column.
    int incl = cnt;
    #pragma unroll
    for (int d = 8; d < 64; d <<= 1) {
        int tmp = __shfl(incl, lane - d, 64);
        if (lane >= d) incl += tmp;
    }
    if (lane >= 56) s_tot[w][lane & (CPB - 1)] = incl;  // wave total per col
    __syncthreads();

    // ---- Phase 2b: add totals of preceding waves (chunk order == wave order)
    int base = incl - cnt;
    for (int w2 = 0; w2 < w; ++w2) base += s_tot[w2][ci];

    // ---- Phase 3: gather matched values, scatter to output ranks ----
    if (colOK) {
        const float* us = user_seq + col;
        while (m) {
            if (base >= K) break;
            int lr = __ffs(m) - 1;
            m &= m - 1;
            out[(size_t)base * B + col] = us[(size_t)(r0 + lr) * B];
            ++base;
        }
    }
}

extern "C" void kernel_launch(void* const* d_in, const int* in_sizes, int n_in,
                              void* d_out, int out_size, void* d_ws, size_t ws_size,
                              hipStream_t stream) {
    const float* user_seq = (const float*)d_in[0];
    // d_in[1] = target_item (unused by the reference computation)
    const int* topics = (const int*)d_in[2];
    const int* tgt    = (const int*)d_in[3];
    // d_in[4] = top_k scalar on device; recover K from out_size instead.

    const int B = in_sizes[1];            // 4096
    const int L = in_sizes[0] / B;        // 2048
    const int K = out_size / B;           // 256
    const int chunkRows = (L + NCH - 1) / NCH;   // 16 for L=2048

    const int grid = (B + CPB - 1) / CPB; // 512 blocks

    if (chunkRows <= 16)
        simhs_kernel<16><<<grid, BLOCK, 0, stream>>>(
            user_seq, topics, tgt, (float*)d_out, L, B, K);
    else
        simhs_kernel<32><<<grid, BLOCK, 0, stream>>>(
            user_seq, topics, tgt, (float*)d_out, L, B, K);
}

// Round 4
// 103.037 us; speedup vs baseline: 1.1149x; 1.1149x over previous
//
#include <hip/hip_runtime.h>

// SIM hard search: per-column stream compaction of first K topic-matching
// values. L=2048, B=4096, K=256 nominal; derived at launch from sizes.
//
// Round 4: two-kernel barrier-free pipeline through d_ws.
//   Kernel A: thread = (32-row word w, col c). Wave = 64 consecutive cols ->
//     every topics load is a full 256B transaction. 32 loads batched in
//     registers (all in flight), build 32-bit match mask, write mask[w][c]
//     (1 MB) to ws.
//   Kernel C: thread = (w, c). Reads its column's 64 mask words (L2-resident,
//     lane-coalesced) to get exclusive prefix 'base' and column total. Zeroes
//     its KPT owned output ranks where rank >= total (disjoint from scatter
//     ranks < total -> no sync needed), then gathers matched user_seq values
//     and scatters to ranks base.. while < K.
// No __syncthreads anywhere; 1024 blocks per kernel.

#define WORD_ROWS 32

__global__ __launch_bounds__(256) void simhs_mask_kernel(
    const int* __restrict__ topics,
    const int* __restrict__ tgt_topic,
    unsigned int* __restrict__ mask,   // [W][B]
    int L, int B, int W)
{
    const int tid = blockIdx.x * blockDim.x + threadIdx.x;
    if (tid >= W * B) return;
    const int c = tid % B;             // consecutive lanes -> consecutive cols
    const int w = tid / B;
    const int tt = tgt_topic[c];
    const int r0 = w * WORD_ROWS;
    const int* tp = topics + (size_t)r0 * B + c;

    unsigned int m = 0u;
    if (r0 + WORD_ROWS <= L) {
        // fast path: batch all 32 strided-but-coalesced loads in registers
        int v[WORD_ROWS];
        #pragma unroll
        for (int i = 0; i < WORD_ROWS; ++i)
            v[i] = tp[(size_t)i * B];
        #pragma unroll
        for (int i = 0; i < WORD_ROWS; ++i)
            m |= (v[i] == tt ? 1u : 0u) << i;
    } else {
        for (int i = 0; r0 + i < L; ++i)
            m |= (tp[(size_t)i * B] == tt ? 1u : 0u) << i;
    }
    mask[tid] = m;
}

__global__ __launch_bounds__(256) void simhs_gather_kernel(
    const float* __restrict__ user_seq,
    const unsigned int* __restrict__ mask,   // [W][B]
    float* __restrict__ out,                 // [K][B]
    int B, int K, int W, int KPT)
{
    const int tid = blockIdx.x * blockDim.x + threadIdx.x;
    if (tid >= W * B) return;
    const int c = tid % B;
    const int w = tid / B;

    // Prefix over this column's words (1 MB array -> L2-resident; each
    // iteration's load is lane-coalesced 256B).
    unsigned int mym = 0u;
    int base = 0, total = 0;
    #pragma unroll 8
    for (int w2 = 0; w2 < W; ++w2) {
        unsigned int mm = mask[(size_t)w2 * B + c];
        if (w2 == w) { mym = mm; base = total; }
        total += __popc(mm);
    }

    // Zero-fill owned ranks that no scatter will write (rank >= total).
    const int k0 = w * KPT;
    #pragma unroll
    for (int j = 0; j < 4; ++j) {
        int k = k0 + j;
        if (j < KPT && k < K && k >= total)
            out[(size_t)k * B + c] = 0.0f;
    }

    // Gather matched values, scatter to output ranks.
    const float* us = user_seq + c;
    const int r0 = w * WORD_ROWS;
    while (mym) {
        if (base >= K) break;
        int lr = __ffs(mym) - 1;
        mym &= mym - 1;
        out[(size_t)base * B + c] = us[(size_t)(r0 + lr) * B];
        ++base;
    }
}

extern "C" void kernel_launch(void* const* d_in, const int* in_sizes, int n_in,
                              void* d_out, int out_size, void* d_ws, size_t ws_size,
                              hipStream_t stream) {
    const float* user_seq = (const float*)d_in[0];
    // d_in[1] = target_item (unused by the reference computation)
    const int* topics = (const int*)d_in[2];
    const int* tgt    = (const int*)d_in[3];
    // d_in[4] = top_k scalar on device; recover K from out_size instead.

    const int B = in_sizes[1];                    // 4096
    const int L = in_sizes[0] / B;                // 2048
    const int K = out_size / B;                   // 256
    const int W = (L + WORD_ROWS - 1) / WORD_ROWS; // 64
    const int KPT = (K + W - 1) / W;              // 4

    unsigned int* mask = (unsigned int*)d_ws;     // W*B*4 = 1 MB

    const int total_threads = W * B;              // 262144
    const int grid = (total_threads + 255) / 256; // 1024 blocks

    simhs_mask_kernel<<<grid, 256, 0, stream>>>(topics, tgt, mask, L, B, W);
    simhs_gather_kernel<<<grid, 256, 0, stream>>>(user_seq, mask, (float*)d_out,
                                                  B, K, W, KPT);
}